// Round 11
// baseline (303.655 us; speedup 1.0000x reference)
//
#include <hip/hip_runtime.h>

// LightGCN propagation: 3x SpMM over fixed COO graph + batched dot epilogue.
// R11: fine-sort fused with SpMM layer 1 ("p4s"): 512 buckets x 293 nodes,
// 512 blocks x 512 thr (exactly 2 blocks/CU, 54KB LDS). Per block: bucket
// edges -> LDS once, 4-copy LDS histogram, wave-shuffle scan, scatter to
// sorted epair (same-XCD L2-hot), then layer-1 per-node register reduction
// reading the hot epair + gathering t0. Kills spmm1's separate launch, its
// cold epair/rowinfo reads, and p4's second coarse pass. Layer 3 computed
// only at batch rows (R10). bf16 rows (R5): compulsory fabric 8x19.2MB/layer.

#define N_USERS 50000
#define N_ITEMS 100000
#define N_NODES 150000
#define N_EDGES 2400000
#define DIM 64
#define BATCH 4096

#define CHUNKS 512
#define CHUNK_EDGES 4688   // 512*4688 = 2400256 >= N_EDGES
#define KB 512             // coarse buckets
#define NPB 293            // nodes per bucket; 512*293 = 150016 >= N_NODES
#define ECAP 5632          // bucket edge cap: mean 4688, sigma 68 -> 13.8 sigma
#define CONVB ((N_NODES * DIM / 4) / 256)   // 9375 conv blocks

typedef unsigned int uint;
typedef float v2f __attribute__((ext_vector_type(2)));

__device__ __forceinline__ uint pack_bf16(float a, float b) {
    uint ua = __float_as_uint(a), ub = __float_as_uint(b);
    ua = (ua + 0x7FFFu + ((ua >> 16) & 1u)) >> 16;   // RTNE
    ub = (ub + 0x7FFFu + ((ub >> 16) & 1u)) >> 16;
    return ua | (ub << 16);
}

__device__ __forceinline__ v2f unpack_bf16x2(uint w) {
    v2f r;
    r.x = __uint_as_float(w << 16);
    r.y = __uint_as_float(w & 0xFFFF0000u);
    return r;
}

// Fused P1 + conv: blocks [0,CHUNKS) per-chunk 512-bucket histogram;
// blocks [CHUNKS, CHUNKS+CONVB) convert fp32 tables -> bf16 concat t0.
__global__ __launch_bounds__(256) void p1_hist_conv(
        const int* __restrict__ dst, int* __restrict__ hist,
        const float* __restrict__ emb_user, const float* __restrict__ emb_item,
        uint2* __restrict__ t0) {
    int t = threadIdx.x;
    if (blockIdx.x < CHUNKS) {
        __shared__ int h[KB];
        int c = blockIdx.x;
        h[t] = 0;
        h[t + 256] = 0;
        __syncthreads();
        int base = c * CHUNK_EDGES;
        for (int i = t; i < CHUNK_EDGES; i += 256) {
            int e = base + i;
            if (e < N_EDGES) atomicAdd(&h[(unsigned)dst[e] / NPB], 1);
        }
        __syncthreads();
        hist[t * CHUNKS + c] = h[t];              // bucket-major
        hist[(t + 256) * CHUNKS + c] = h[t + 256];
    } else {
        int i = (blockIdx.x - CHUNKS) * 256 + t;  // float4 index, 2.4M total
        const int userN4 = N_USERS * DIM / 4;     // 800000
        float4 v;
        if (i < userN4) v = ((const float4*)emb_user)[i];
        else            v = ((const float4*)emb_item)[i - userN4];
        t0[i] = make_uint2(pack_bf16(v.x, v.y), pack_bf16(v.z, v.w));
    }
}

// P2a: per-bucket exclusive scan over its 512 chunk counts; emit totals.
__global__ __launch_bounds__(256) void p2a_scan(int* __restrict__ hist,
                                                int* __restrict__ tot) {
    int b = blockIdx.x, t = threadIdx.x;
    int i0 = b * CHUNKS + 2 * t;
    int v0 = hist[i0], v1 = hist[i0 + 1];
    int s = v0 + v1;
    __shared__ int sm[256];
    sm[t] = s;
    __syncthreads();
    for (int o = 1; o < 256; o <<= 1) {
        int add = (t >= o) ? sm[t - o] : 0;
        __syncthreads();
        sm[t] += add;
        __syncthreads();
    }
    int excl = sm[t] - s;
    hist[i0] = excl;
    hist[i0 + 1] = excl + v0;
    if (t == 255) tot[b] = excl + s;
}

// P2b: exclusive scan of the 512 bucket totals -> bucket_base[513]
__global__ __launch_bounds__(512) void p2b_scan(const int* __restrict__ tot,
                                                int* __restrict__ bucket_base) {
    int t = threadIdx.x;
    int v = tot[t];
    __shared__ int sm[512];
    sm[t] = v;
    __syncthreads();
    for (int o = 1; o < 512; o <<= 1) {
        int add = (t >= o) ? sm[t - o] : 0;
        __syncthreads();
        sm[t] += add;
        __syncthreads();
    }
    bucket_base[t] = sm[t] - v;
    if (t == 511) bucket_base[512] = sm[t];
}

// P3: coarse partition into block-owned per-bucket runs.
// Payload packed: x = src | dst_local<<18 (src<2^18, dl<512), y = val bits.
__global__ __launch_bounds__(256) void p3_part(const int* __restrict__ src,
                                               const int* __restrict__ dstA,
                                               const float* __restrict__ vals,
                                               const int* __restrict__ hist,
                                               const int* __restrict__ bucket_base,
                                               int2* __restrict__ coarse) {
    __shared__ int cur[KB];
    int c = blockIdx.x, t = threadIdx.x;
    cur[t] = bucket_base[t] + hist[t * CHUNKS + c];
    cur[t + 256] = bucket_base[t + 256] + hist[(t + 256) * CHUNKS + c];
    __syncthreads();
    int base = c * CHUNK_EDGES;
    for (int i = t; i < CHUNK_EDGES; i += 256) {
        int e = base + i;
        if (e < N_EDGES) {
            int d = dstA[e];
            int b = (int)((unsigned)d / NPB);
            int dl = d - b * NPB;
            int p = atomicAdd(&cur[b], 1);
            coarse[p] = make_int2(src[e] | (dl << 18), __float_as_int(vals[e]));
        }
    }
}

// P4S: per-bucket fine sort + FUSED layer-1 SpMM.
// Phase A: bucket edges -> LDS (single coarse read); 4-copy histogram;
// wave-shuffle scan; rowinfo; scatter LDS -> sorted global epair.
// Phase B: per-node register reduction (R6 spmm form) reading the
// just-written (same-XCD L2-hot) epair run, gathering t0, writing x1.
__global__ __launch_bounds__(512) void p4s_sort_spmm(
        const int2* __restrict__ coarse, const int* __restrict__ bucket_base,
        const uint* __restrict__ xin, int2* __restrict__ epair,
        uint* __restrict__ rowinfo, uint* __restrict__ xout) {
    __shared__ int2 eds[ECAP];        // 45056 B
    __shared__ int hist4[4][320];     // 5120 B
    __shared__ int cntT[320];
    __shared__ int rs_[320];
    __shared__ int cur_[320];
    __shared__ int wsum[8];
    int k = blockIdx.x, t = threadIdx.x;
    int base = bucket_base[k];
    int ne = min(bucket_base[k + 1] - base, ECAP);
    for (int i = t; i < ne; i += 512) eds[i] = coarse[base + i];
    for (int i = t; i < 4 * 320; i += 512) ((int*)hist4)[i] = 0;
    __syncthreads();
    int wp = t >> 7;                  // wave-pair 0..3
    for (int i = t; i < ne; i += 512)
        atomicAdd(&hist4[wp][eds[i].x >> 18], 1);
    __syncthreads();
    int wid = t >> 6, lane = t & 63;
    int v = 0;
    if (t < 320) {
        v = hist4[0][t] + hist4[1][t] + hist4[2][t] + hist4[3][t];
        cntT[t] = v;
    }
    if (t < 320) {                    // waves 0..4 exactly (320 = 5*64)
        int incl = v;
#pragma unroll
        for (int o = 1; o < 64; o <<= 1) {
            int add = __shfl_up(incl, o, 64);
            if (lane >= o) incl += add;
        }
        rs_[t] = incl - v;
        if (lane == 63) wsum[wid] = incl;
    }
    __syncthreads();
    if (t < 64) {
        int vv = (lane < 5) ? wsum[lane] : 0;
        int inc2 = vv;
#pragma unroll
        for (int o = 1; o < 8; o <<= 1) {
            int add = __shfl_up(inc2, o, 64);
            if (lane >= o) inc2 += add;
        }
        if (lane < 5) wsum[lane] = inc2 - vv;
    }
    __syncthreads();
    if (t < 320) rs_[t] += wsum[wid];
    __syncthreads();
    int nodes0 = k * NPB;
    int nb = min(NPB, N_NODES - nodes0);
    if (t < nb)
        rowinfo[nodes0 + t] = (uint)(base + rs_[t]) | ((uint)cntT[t] << 22);
    if (t < 320) cur_[t] = rs_[t];
    __syncthreads();
    for (int i = t; i < ne; i += 512) {
        int2 ev = eds[i];
        int dl = ev.x >> 18;
        int p = atomicAdd(&cur_[dl], 1);
        epair[base + p] = make_int2(ev.x & 0x3FFFF, ev.y);
    }
    __syncthreads();   // drains vmem: epair writes visible via this XCD's L2
    // ---- Phase B: layer-1 reduction for this bucket's nodes ----
    int g = lane >> 3;        // edge group 0..7
    int l = lane & 7;         // uint4 slot within 128B row
    for (int nl = wid; nl < nb; nl += 8) {
        int sg = base + rs_[nl];
        int e = sg + cntT[nl];
        v2f a0 = {0.f, 0.f}, a1 = {0.f, 0.f}, a2 = {0.f, 0.f}, a3 = {0.f, 0.f};
        for (int j0 = sg + g; j0 < e; j0 += 16) {
            int j1 = j0 + 8;
            bool p1 = j1 < e;
            int2 ev0 = epair[j0];
            int2 ev1 = epair[p1 ? j1 : j0];
            float v0 = __int_as_float(ev0.y);
            float v1 = p1 ? __int_as_float(ev1.y) : 0.f;
            uint4 r0 = ((const uint4*)(xin + (size_t)ev0.x * 32))[l];
            uint4 r1 = ((const uint4*)(xin + (size_t)ev1.x * 32))[l];
            a0 += v0 * unpack_bf16x2(r0.x);
            a1 += v0 * unpack_bf16x2(r0.y);
            a2 += v0 * unpack_bf16x2(r0.z);
            a3 += v0 * unpack_bf16x2(r0.w);
            a0 += v1 * unpack_bf16x2(r1.x);
            a1 += v1 * unpack_bf16x2(r1.y);
            a2 += v1 * unpack_bf16x2(r1.z);
            a3 += v1 * unpack_bf16x2(r1.w);
        }
#pragma unroll
        for (int off = 8; off < 64; off <<= 1) {
            a0.x += __shfl_xor(a0.x, off, 64);
            a0.y += __shfl_xor(a0.y, off, 64);
            a1.x += __shfl_xor(a1.x, off, 64);
            a1.y += __shfl_xor(a1.y, off, 64);
            a2.x += __shfl_xor(a2.x, off, 64);
            a2.y += __shfl_xor(a2.y, off, 64);
            a3.x += __shfl_xor(a3.x, off, 64);
            a3.y += __shfl_xor(a3.y, off, 64);
        }
        if (g == 0) {
            uint4 o;
            o.x = pack_bf16(a0.x, a0.y);
            o.y = pack_bf16(a1.x, a1.y);
            o.z = pack_bf16(a2.x, a2.y);
            o.w = pack_bf16(a3.x, a3.y);
            ((uint4*)(xout + (size_t)(nodes0 + nl) * 32))[l] = o;
        }
    }
}

// SpMM over bf16 rows (layer 2). R6 form: one wave per node; 8 groups x 8
// lanes; 2x unrolled -> 16 edges in flight; shfl_xor reduce; group 0 writes.
__global__ __launch_bounds__(256) void spmm_kernel(
        const uint* __restrict__ rowinfo, const int2* __restrict__ epair,
        const uint* __restrict__ xin, uint* __restrict__ xout) {
    int n = (blockIdx.x * 256 + threadIdx.x) >> 6;   // 150000 = 4*37500 exact
    int lane = threadIdx.x & 63;
    int g = lane >> 3;
    int l = lane & 7;
    uint ri = rowinfo[n];
    int s = (int)(ri & 0x3FFFFFu);
    int e = s + (int)(ri >> 22);
    v2f a0 = {0.f, 0.f}, a1 = {0.f, 0.f}, a2 = {0.f, 0.f}, a3 = {0.f, 0.f};
    for (int j0 = s + g; j0 < e; j0 += 16) {
        int j1 = j0 + 8;
        bool p1 = j1 < e;
        int2 ev0 = epair[j0];
        int2 ev1 = epair[p1 ? j1 : j0];
        float v0 = __int_as_float(ev0.y);
        float v1 = p1 ? __int_as_float(ev1.y) : 0.f;
        uint4 r0 = ((const uint4*)(xin + (size_t)ev0.x * 32))[l];
        uint4 r1 = ((const uint4*)(xin + (size_t)ev1.x * 32))[l];
        a0 += v0 * unpack_bf16x2(r0.x);
        a1 += v0 * unpack_bf16x2(r0.y);
        a2 += v0 * unpack_bf16x2(r0.z);
        a3 += v0 * unpack_bf16x2(r0.w);
        a0 += v1 * unpack_bf16x2(r1.x);
        a1 += v1 * unpack_bf16x2(r1.y);
        a2 += v1 * unpack_bf16x2(r1.z);
        a3 += v1 * unpack_bf16x2(r1.w);
    }
#pragma unroll
    for (int off = 8; off < 64; off <<= 1) {
        a0.x += __shfl_xor(a0.x, off, 64);
        a0.y += __shfl_xor(a0.y, off, 64);
        a1.x += __shfl_xor(a1.x, off, 64);
        a1.y += __shfl_xor(a1.y, off, 64);
        a2.x += __shfl_xor(a2.x, off, 64);
        a2.y += __shfl_xor(a2.y, off, 64);
        a3.x += __shfl_xor(a3.x, off, 64);
        a3.y += __shfl_xor(a3.y, off, 64);
    }
    if (g == 0) {
        uint4 o;
        o.x = pack_bf16(a0.x, a0.y);
        o.y = pack_bf16(a1.x, a1.y);
        o.z = pack_bf16(a2.x, a2.y);
        o.w = pack_bf16(a3.x, a3.y);
        ((uint4*)(xout + (size_t)n * 32))[l] = o;
    }
}

// Layer-3 restricted to batch rows: one wave per batch node (2*BATCH waves).
// x3[n] = sum val*x2[src]; add x0 (fp32) + x1 + x2 (bf16); store fp32 row.
__global__ __launch_bounds__(256) void batch_row_kernel(
        const int* __restrict__ users, const int* __restrict__ items,
        const float* __restrict__ emb_user, const float* __restrict__ emb_item,
        const uint* __restrict__ x1, const uint* __restrict__ x2,
        const uint* __restrict__ rowinfo, const int2* __restrict__ epair,
        float4* __restrict__ rows) {
    int w = (blockIdx.x * 256 + threadIdx.x) >> 6;   // 0..2*BATCH-1
    int lane = threadIdx.x & 63;
    int g = lane >> 4;
    int l = lane & 15;        // uint2 slot: dims 4l..4l+3
    bool isU = w < BATCH;
    int b = isU ? w : w - BATCH;
    int idx = isU ? users[b] : items[b];
    int n = isU ? idx : N_USERS + idx;
    uint ri = rowinfo[n];
    int s = (int)(ri & 0x3FFFFFu);
    int e = s + (int)(ri >> 22);
    v2f a0 = {0.f, 0.f}, a1 = {0.f, 0.f};
    for (int j0 = s + g; j0 < e; j0 += 16) {
        int2 ev[4];
        float vv[4];
        uint2 rr[4];
#pragma unroll
        for (int u = 0; u < 4; ++u) {
            int j = j0 + 4 * u;
            bool p = (u == 0) || (j < e);
            ev[u] = epair[p ? j : j0];
            vv[u] = p ? __int_as_float(ev[u].y) : 0.f;
        }
#pragma unroll
        for (int u = 0; u < 4; ++u)
            rr[u] = ((const uint2*)(x2 + (size_t)ev[u].x * 32))[l];
#pragma unroll
        for (int u = 0; u < 4; ++u) {
            a0 += vv[u] * unpack_bf16x2(rr[u].x);
            a1 += vv[u] * unpack_bf16x2(rr[u].y);
        }
    }
#pragma unroll
    for (int off = 16; off < 64; off <<= 1) {
        a0.x += __shfl_xor(a0.x, off, 64);
        a0.y += __shfl_xor(a0.y, off, 64);
        a1.x += __shfl_xor(a1.x, off, 64);
        a1.y += __shfl_xor(a1.y, off, 64);
    }
    if (g == 0) {
        const float* t0row = isU ? (emb_user + (size_t)idx * DIM)
                                 : (emb_item + (size_t)idx * DIM);
        float4 x0 = ((const float4*)t0row)[l];
        uint2 w1 = ((const uint2*)(x1 + (size_t)n * 32))[l];
        uint2 w2 = ((const uint2*)(x2 + (size_t)n * 32))[l];
        v2f b10 = unpack_bf16x2(w1.x), b11 = unpack_bf16x2(w1.y);
        v2f b20 = unpack_bf16x2(w2.x), b21 = unpack_bf16x2(w2.y);
        float4 r;
        r.x = x0.x + b10.x + b20.x + a0.x;
        r.y = x0.y + b10.y + b20.y + a0.y;
        r.z = x0.z + b11.x + b21.x + a1.x;
        r.w = x0.w + b11.y + b21.y + a1.y;
        rows[(size_t)w * 16 + l] = r;
    }
}

// gamma[b] = dot(rows[b], rows[BATCH+b]) / 16
__global__ __launch_bounds__(256) void dot_kernel(const float* __restrict__ rows,
                                                  float* __restrict__ out) {
    int t = blockIdx.x * 256 + threadIdx.x;
    int b = t >> 6;
    int lane = t & 63;
    float p = rows[(size_t)b * DIM + lane] * rows[(size_t)(BATCH + b) * DIM + lane];
#pragma unroll
    for (int o = 32; o > 0; o >>= 1) p += __shfl_down(p, o, 64);
    if (lane == 0) out[b] = p * (1.0f / 16.0f);
}

extern "C" void kernel_launch(void* const* d_in, const int* in_sizes, int n_in,
                              void* d_out, int out_size, void* d_ws, size_t ws_size,
                              hipStream_t stream) {
    const float* emb_user = (const float*)d_in[0];
    const float* emb_item = (const float*)d_in[1];
    const float* vals     = (const float*)d_in[2];
    const int*   src      = (const int*)d_in[3];
    const int*   dst      = (const int*)d_in[4];
    const int*   users    = (const int*)d_in[5];
    const int*   items    = (const int*)d_in[6];
    float* out = (float*)d_out;

    char* ws = (char*)d_ws;
    size_t off = 0;
    auto walloc = [&](size_t bytes) -> void* {
        void* p = ws + off;
        off += (bytes + 255) & ~(size_t)255;
        return p;
    };
    const size_t ROWB = (size_t)N_NODES * DIM * 2;                  // 19.2 MB
    uint* t0          = (uint*)walloc(ROWB);                        // bf16 x0
    uint* x1          = (uint*)walloc(ROWB);
    uint* x2          = (uint*)walloc(ROWB);
    int2* coarse      = (int2*)walloc((size_t)N_EDGES * 8);         // 19.2 MB
    int2* epair       = (int2*)walloc((size_t)N_EDGES * 8);         // 19.2 MB
    int*  hist        = (int*) walloc((size_t)CHUNKS * KB * 4);     // 1 MB
    int*  tot         = (int*) walloc((size_t)KB * 4);
    int*  bucket_base = (int*) walloc((size_t)(KB + 1) * 4);
    uint* rowinfo     = (uint*)walloc((size_t)N_NODES * 4);
    // rows (2MB) aliases coarse: coarse dead after p4s reads it.
    float4* rows = (float4*)coarse;

    // Build (+ fused bf16 conversion)
    p1_hist_conv<<<CHUNKS + CONVB, 256, 0, stream>>>(dst, hist, emb_user, emb_item, (uint2*)t0);
    p2a_scan<<<KB, 256, 0, stream>>>(hist, tot);
    p2b_scan<<<1, 512, 0, stream>>>(tot, bucket_base);
    p3_part<<<CHUNKS, 256, 0, stream>>>(src, dst, vals, hist, bucket_base, coarse);

    // Fine sort + layer-1 SpMM fused
    p4s_sort_spmm<<<KB, 512, 0, stream>>>(coarse, bucket_base, t0, epair, rowinfo, x1);

    // Layer 2 (full), layer 3 (batch rows only) + dot
    spmm_kernel<<<N_NODES / 4, 256, 0, stream>>>(rowinfo, epair, x1, x2);
    batch_row_kernel<<<(2 * BATCH) / 4, 256, 0, stream>>>(
        users, items, emb_user, emb_item, x1, x2, rowinfo, epair, rows);
    dot_kernel<<<(BATCH * 64) / 256, 256, 0, stream>>>((const float*)rows, out);
}

// Round 12
// 290.798 us; speedup vs baseline: 1.0442x; 1.0442x over previous
//
#include <hip/hip_runtime.h>

// LightGCN propagation: 3x SpMM over fixed COO graph + batched dot epilogue.
// R12: build collapsed to TWO kernels via fixed-capacity segmented buckets.
// part: per-chunk LDS histogram + ONE global atomicAdd per (block,bucket)
// reserves space in coarse[b*ECAP..] — no global scan kernels, no hist
// buffer, dst read once (p1+p2a+p2b+p3 were ~150us at a ~35us roofline).
// p4f: fine sort per bucket IN PLACE (LDS staging, wave-shuffle scan),
// emits rowinfo (start=k*ECAP+rs fits 22 bits). spmm kept standalone at
// full occupancy (R11: fusing it into LDS-heavy blocks cost 2x occupancy).
// Layer 3 only at batch rows (R10). bf16 rows (R5): fabric 8x19.2MB/layer.

#define N_USERS 50000
#define N_ITEMS 100000
#define N_NODES 150000
#define N_EDGES 2400000
#define DIM 64
#define BATCH 4096

#define CHUNKS 512
#define CHUNK_EDGES 4688   // 512*4688 = 2400256 >= N_EDGES
#define KB 512             // buckets
#define NPB 293            // nodes per bucket; 512*293 = 150016 >= N_NODES
#define ECAP 5632          // bucket capacity: mean 4688, sigma 68 -> 13.8 sigma
#define CONVB ((N_NODES * DIM / 4) / 256)   // 9375 conv blocks

typedef unsigned int uint;
typedef float v2f __attribute__((ext_vector_type(2)));

__device__ __forceinline__ uint pack_bf16(float a, float b) {
    uint ua = __float_as_uint(a), ub = __float_as_uint(b);
    ua = (ua + 0x7FFFu + ((ua >> 16) & 1u)) >> 16;   // RTNE
    ub = (ub + 0x7FFFu + ((ub >> 16) & 1u)) >> 16;
    return ua | (ub << 16);
}

__device__ __forceinline__ v2f unpack_bf16x2(uint w) {
    v2f r;
    r.x = __uint_as_float(w << 16);
    r.y = __uint_as_float(w & 0xFFFF0000u);
    return r;
}

// PART: one-kernel partition (+ fused bf16 conversion on extra blocks).
// Chunk blocks: pass1 dst -> LDS binfo + LDS hist; reserve global space per
// bucket (one atomicAdd each); pass2 src/vals -> scatter into coarse region.
__global__ __launch_bounds__(256) void part_kernel(
        const int* __restrict__ src, const int* __restrict__ dstA,
        const float* __restrict__ vals, int* __restrict__ gcur,
        int2* __restrict__ coarse,
        const float* __restrict__ emb_user, const float* __restrict__ emb_item,
        uint2* __restrict__ t0) {
    int t = threadIdx.x;
    if (blockIdx.x >= CHUNKS) {
        int i = (blockIdx.x - CHUNKS) * 256 + t;  // float4 index, 2.4M total
        const int userN4 = N_USERS * DIM / 4;     // 800000
        float4 v;
        if (i < userN4) v = ((const float4*)emb_user)[i];
        else            v = ((const float4*)emb_item)[i - userN4];
        t0[i] = make_uint2(pack_bf16(v.x, v.y), pack_bf16(v.z, v.w));
        return;
    }
    __shared__ int binfo[CHUNK_EDGES];   // b<<9 | dl  (18.75 KB)
    __shared__ int h[KB];
    __shared__ int cur[KB];
    int c = blockIdx.x;
    h[t] = 0; h[t + 256] = 0;
    __syncthreads();
    int base = c * CHUNK_EDGES;
    for (int i = t; i < CHUNK_EDGES; i += 256) {
        int e = base + i;
        if (e < N_EDGES) {
            int d = dstA[e];
            int b = (int)((unsigned)d / NPB);     // const divisor -> magic mul
            int dl = d - b * NPB;
            binfo[i] = (b << 9) | dl;
            atomicAdd(&h[b], 1);
        } else binfo[i] = -1;
    }
    __syncthreads();
    cur[t] = atomicAdd(&gcur[t], h[t]);                 // reserve runs
    cur[t + 256] = atomicAdd(&gcur[t + 256], h[t + 256]);
    __syncthreads();
    for (int i = t; i < CHUNK_EDGES; i += 256) {
        int info = binfo[i];
        if (info >= 0) {
            int b = info >> 9;
            int dl = info & 511;
            int p = atomicAdd(&cur[b], 1);
            if (p < ECAP)
                coarse[b * ECAP + p] = make_int2(src[base + i] | (dl << 18),
                                                 __float_as_int(vals[base + i]));
        }
    }
}

// P4F: per-bucket fine sort IN PLACE. Edges -> LDS (one read), histogram,
// wave-shuffle scan, rowinfo emit, sorted scatter back into same region.
__global__ __launch_bounds__(512) void p4f_fine(int2* __restrict__ coarse,
                                                const int* __restrict__ gcur,
                                                uint* __restrict__ rowinfo) {
    __shared__ int2 eds[ECAP];        // 45056 B
    __shared__ int cnt[320];
    __shared__ int rs_[320];
    __shared__ int cur_[320];
    __shared__ int wsum[8];
    int k = blockIdx.x, t = threadIdx.x;
    int rbase = k * ECAP;
    int ne = min(gcur[k], ECAP);
    for (int i = t; i < ne; i += 512) eds[i] = coarse[rbase + i];
    if (t < 320) cnt[t] = 0;
    __syncthreads();
    for (int i = t; i < ne; i += 512)
        atomicAdd(&cnt[eds[i].x >> 18], 1);
    __syncthreads();
    int wid = t >> 6, lane = t & 63;
    if (t < 320) {                    // waves 0..4 (320 = 5*64)
        int v = cnt[t];
        int incl = v;
#pragma unroll
        for (int o = 1; o < 64; o <<= 1) {
            int add = __shfl_up(incl, o, 64);
            if (lane >= o) incl += add;
        }
        rs_[t] = incl - v;
        if (lane == 63) wsum[wid] = incl;
    }
    __syncthreads();
    if (t < 64) {
        int vv = (lane < 5) ? wsum[lane] : 0;
        int inc2 = vv;
#pragma unroll
        for (int o = 1; o < 8; o <<= 1) {
            int add = __shfl_up(inc2, o, 64);
            if (lane >= o) inc2 += add;
        }
        if (lane < 5) wsum[lane] = inc2 - vv;
    }
    __syncthreads();
    if (t < 320) rs_[t] += wsum[wid];
    __syncthreads();
    int nodes0 = k * NPB;
    int nb = min(NPB, N_NODES - nodes0);
    if (t < nb)
        rowinfo[nodes0 + t] = (uint)(rbase + rs_[t]) | ((uint)cnt[t] << 22);
    if (t < 320) cur_[t] = rs_[t];
    __syncthreads();
    for (int i = t; i < ne; i += 512) {
        int2 ev = eds[i];
        int dl = ev.x >> 18;
        int p = atomicAdd(&cur_[dl], 1);
        coarse[rbase + p] = make_int2(ev.x & 0x3FFFF, ev.y);   // strip dl
    }
}

// SpMM over bf16 rows (128B/row). R6/R10 form: one wave per node; 8 groups
// x 8 lanes; 2x unrolled -> 16 edges in flight; shfl_xor reduce.
__global__ __launch_bounds__(256) void spmm_kernel(
        const uint* __restrict__ rowinfo, const int2* __restrict__ epair,
        const uint* __restrict__ xin, uint* __restrict__ xout) {
    int n = (blockIdx.x * 256 + threadIdx.x) >> 6;   // 150000 = 4*37500 exact
    int lane = threadIdx.x & 63;
    int g = lane >> 3;
    int l = lane & 7;
    uint ri = rowinfo[n];
    int s = (int)(ri & 0x3FFFFFu);
    int e = s + (int)(ri >> 22);
    v2f a0 = {0.f, 0.f}, a1 = {0.f, 0.f}, a2 = {0.f, 0.f}, a3 = {0.f, 0.f};
    for (int j0 = s + g; j0 < e; j0 += 16) {
        int j1 = j0 + 8;
        bool p1 = j1 < e;
        int2 ev0 = epair[j0];
        int2 ev1 = epair[p1 ? j1 : j0];
        float v0 = __int_as_float(ev0.y);
        float v1 = p1 ? __int_as_float(ev1.y) : 0.f;
        uint4 r0 = ((const uint4*)(xin + (size_t)ev0.x * 32))[l];
        uint4 r1 = ((const uint4*)(xin + (size_t)ev1.x * 32))[l];
        a0 += v0 * unpack_bf16x2(r0.x);
        a1 += v0 * unpack_bf16x2(r0.y);
        a2 += v0 * unpack_bf16x2(r0.z);
        a3 += v0 * unpack_bf16x2(r0.w);
        a0 += v1 * unpack_bf16x2(r1.x);
        a1 += v1 * unpack_bf16x2(r1.y);
        a2 += v1 * unpack_bf16x2(r1.z);
        a3 += v1 * unpack_bf16x2(r1.w);
    }
#pragma unroll
    for (int off = 8; off < 64; off <<= 1) {
        a0.x += __shfl_xor(a0.x, off, 64);
        a0.y += __shfl_xor(a0.y, off, 64);
        a1.x += __shfl_xor(a1.x, off, 64);
        a1.y += __shfl_xor(a1.y, off, 64);
        a2.x += __shfl_xor(a2.x, off, 64);
        a2.y += __shfl_xor(a2.y, off, 64);
        a3.x += __shfl_xor(a3.x, off, 64);
        a3.y += __shfl_xor(a3.y, off, 64);
    }
    if (g == 0) {
        uint4 o;
        o.x = pack_bf16(a0.x, a0.y);
        o.y = pack_bf16(a1.x, a1.y);
        o.z = pack_bf16(a2.x, a2.y);
        o.w = pack_bf16(a3.x, a3.y);
        ((uint4*)(xout + (size_t)n * 32))[l] = o;
    }
}

// Layer-3 restricted to batch rows: one wave per batch node (2*BATCH waves).
// x3[n] = sum val*x2[src]; add x0 (fp32) + x1 + x2 (bf16); store fp32 row.
__global__ __launch_bounds__(256) void batch_row_kernel(
        const int* __restrict__ users, const int* __restrict__ items,
        const float* __restrict__ emb_user, const float* __restrict__ emb_item,
        const uint* __restrict__ x1, const uint* __restrict__ x2,
        const uint* __restrict__ rowinfo, const int2* __restrict__ epair,
        float4* __restrict__ rows) {
    int w = (blockIdx.x * 256 + threadIdx.x) >> 6;   // 0..2*BATCH-1
    int lane = threadIdx.x & 63;
    int g = lane >> 4;
    int l = lane & 15;        // uint2 slot: dims 4l..4l+3
    bool isU = w < BATCH;
    int b = isU ? w : w - BATCH;
    int idx = isU ? users[b] : items[b];
    int n = isU ? idx : N_USERS + idx;
    uint ri = rowinfo[n];
    int s = (int)(ri & 0x3FFFFFu);
    int e = s + (int)(ri >> 22);
    v2f a0 = {0.f, 0.f}, a1 = {0.f, 0.f};
    for (int j0 = s + g; j0 < e; j0 += 16) {
        int2 ev[4];
        float vv[4];
        uint2 rr[4];
#pragma unroll
        for (int u = 0; u < 4; ++u) {
            int j = j0 + 4 * u;
            bool p = (u == 0) || (j < e);
            ev[u] = epair[p ? j : j0];
            vv[u] = p ? __int_as_float(ev[u].y) : 0.f;
        }
#pragma unroll
        for (int u = 0; u < 4; ++u)
            rr[u] = ((const uint2*)(x2 + (size_t)ev[u].x * 32))[l];
#pragma unroll
        for (int u = 0; u < 4; ++u) {
            a0 += vv[u] * unpack_bf16x2(rr[u].x);
            a1 += vv[u] * unpack_bf16x2(rr[u].y);
        }
    }
#pragma unroll
    for (int off = 16; off < 64; off <<= 1) {
        a0.x += __shfl_xor(a0.x, off, 64);
        a0.y += __shfl_xor(a0.y, off, 64);
        a1.x += __shfl_xor(a1.x, off, 64);
        a1.y += __shfl_xor(a1.y, off, 64);
    }
    if (g == 0) {
        const float* t0row = isU ? (emb_user + (size_t)idx * DIM)
                                 : (emb_item + (size_t)idx * DIM);
        float4 x0 = ((const float4*)t0row)[l];
        uint2 w1 = ((const uint2*)(x1 + (size_t)n * 32))[l];
        uint2 w2 = ((const uint2*)(x2 + (size_t)n * 32))[l];
        v2f b10 = unpack_bf16x2(w1.x), b11 = unpack_bf16x2(w1.y);
        v2f b20 = unpack_bf16x2(w2.x), b21 = unpack_bf16x2(w2.y);
        float4 r;
        r.x = x0.x + b10.x + b20.x + a0.x;
        r.y = x0.y + b10.y + b20.y + a0.y;
        r.z = x0.z + b11.x + b21.x + a1.x;
        r.w = x0.w + b11.y + b21.y + a1.y;
        rows[(size_t)w * 16 + l] = r;
    }
}

// gamma[b] = dot(rows[b], rows[BATCH+b]) / 16
__global__ __launch_bounds__(256) void dot_kernel(const float* __restrict__ rows,
                                                  float* __restrict__ out) {
    int t = blockIdx.x * 256 + threadIdx.x;
    int b = t >> 6;
    int lane = t & 63;
    float p = rows[(size_t)b * DIM + lane] * rows[(size_t)(BATCH + b) * DIM + lane];
#pragma unroll
    for (int o = 32; o > 0; o >>= 1) p += __shfl_down(p, o, 64);
    if (lane == 0) out[b] = p * (1.0f / 16.0f);
}

extern "C" void kernel_launch(void* const* d_in, const int* in_sizes, int n_in,
                              void* d_out, int out_size, void* d_ws, size_t ws_size,
                              hipStream_t stream) {
    const float* emb_user = (const float*)d_in[0];
    const float* emb_item = (const float*)d_in[1];
    const float* vals     = (const float*)d_in[2];
    const int*   src      = (const int*)d_in[3];
    const int*   dst      = (const int*)d_in[4];
    const int*   users    = (const int*)d_in[5];
    const int*   items    = (const int*)d_in[6];
    float* out = (float*)d_out;

    char* ws = (char*)d_ws;
    size_t off = 0;
    auto walloc = [&](size_t bytes) -> void* {
        void* p = ws + off;
        off += (bytes + 255) & ~(size_t)255;
        return p;
    };
    const size_t ROWB = (size_t)N_NODES * DIM * 2;                  // 19.2 MB
    uint* t0          = (uint*)walloc(ROWB);                        // bf16 x0
    uint* x1          = (uint*)walloc(ROWB);
    uint* x2          = (uint*)walloc(ROWB);
    int2* coarse      = (int2*)walloc((size_t)KB * ECAP * 8);       // 23.1 MB
    int*  gcur        = (int*) walloc((size_t)KB * 4);
    uint* rowinfo     = (uint*)walloc((size_t)N_NODES * 4);
    float4* rows      = (float4*)walloc((size_t)2 * BATCH * DIM * 4); // 2 MB

    hipMemsetAsync(gcur, 0, (size_t)KB * 4, stream);

    // Build: single-pass partition (+ fused conv), then in-place fine sort
    part_kernel<<<CHUNKS + CONVB, 256, 0, stream>>>(
        src, dst, vals, gcur, coarse, emb_user, emb_item, (uint2*)t0);
    p4f_fine<<<KB, 512, 0, stream>>>(coarse, gcur, rowinfo);

    // Layers 1,2 full; layer 3 batch-only + dot
    spmm_kernel<<<N_NODES / 4, 256, 0, stream>>>(rowinfo, coarse, t0, x1);
    spmm_kernel<<<N_NODES / 4, 256, 0, stream>>>(rowinfo, coarse, x1, x2);
    batch_row_kernel<<<(2 * BATCH) / 4, 256, 0, stream>>>(
        users, items, emb_user, emb_item, x1, x2, rowinfo, coarse, rows);
    dot_kernel<<<(BATCH * 64) / 256, 256, 0, stream>>>((const float*)rows, out);
}

// Round 13
// 285.214 us; speedup vs baseline: 1.0647x; 1.0196x over previous
//
#include <hip/hip_runtime.h>

// LightGCN propagation: 3x SpMM over fixed COO graph + batched dot epilogue.
// R13: partition re-shaped for fat runs. 128 chunks x 18750 edges into 256
// super-buckets of 586 nodes -> (block,bucket) runs avg 73 edges = 586B
// (~9 full lines; R12's 9-edge/73B runs caused 82MB of partial-line RMW
// writes). No binfo LDS (pass 2 re-reads L2-hot dst) -> 2KB LDS, full
// occupancy. Fine sort in place per super-bucket (80KB LDS, 1024thr).
// spmm standalone at full occupancy (R11 lesson). Layer 3 batch-only (R10).
// bf16 rows (R5): compulsory fabric 8 XCD x 19.2MB/layer.

#define N_USERS 50000
#define N_ITEMS 100000
#define N_NODES 150000
#define N_EDGES 2400000
#define DIM 64
#define BATCH 4096

#define CHUNKS 128
#define CHUNK_EDGES 18750  // 128*18750 = 2400000 exact
#define KB 256             // super-buckets
#define NPB 586            // nodes per bucket; 256*586 = 150016 >= N_NODES
#define ECAP 10240         // bucket capacity: mean 9375, sigma 97 -> +8.9 sigma
#define CONVB 4688         // ceil(2400000 float4 / 512)

typedef unsigned int uint;
typedef float v2f __attribute__((ext_vector_type(2)));

__device__ __forceinline__ uint pack_bf16(float a, float b) {
    uint ua = __float_as_uint(a), ub = __float_as_uint(b);
    ua = (ua + 0x7FFFu + ((ua >> 16) & 1u)) >> 16;   // RTNE
    ub = (ub + 0x7FFFu + ((ub >> 16) & 1u)) >> 16;
    return ua | (ub << 16);
}

__device__ __forceinline__ v2f unpack_bf16x2(uint w) {
    v2f r;
    r.x = __uint_as_float(w << 16);
    r.y = __uint_as_float(w & 0xFFFF0000u);
    return r;
}

// PART: blocks [0,CHUNKS): hist pass over dst (LDS, 2KB) -> one global
// atomicAdd per bucket reserves a fat run -> scatter pass re-reads dst
// (L2-hot) + src/vals. Blocks [CHUNKS,..): fp32 tables -> bf16 concat t0.
__global__ __launch_bounds__(512) void part_kernel(
        const int* __restrict__ src, const int* __restrict__ dstA,
        const float* __restrict__ vals, int* __restrict__ gcur,
        int2* __restrict__ coarse,
        const float* __restrict__ emb_user, const float* __restrict__ emb_item,
        uint2* __restrict__ t0) {
    int t = threadIdx.x;
    if (blockIdx.x >= CHUNKS) {
        int i = (blockIdx.x - CHUNKS) * 512 + t;  // float4 index, 2.4M total
        if (i < N_NODES * DIM / 4) {
            const int userN4 = N_USERS * DIM / 4; // 800000
            float4 v;
            if (i < userN4) v = ((const float4*)emb_user)[i];
            else            v = ((const float4*)emb_item)[i - userN4];
            t0[i] = make_uint2(pack_bf16(v.x, v.y), pack_bf16(v.z, v.w));
        }
        return;
    }
    __shared__ int h[KB];
    __shared__ int cur[KB];
    int c = blockIdx.x;
    if (t < KB) h[t] = 0;
    __syncthreads();
    int base = c * CHUNK_EDGES;
    for (int i = t; i < CHUNK_EDGES; i += 512) {
        int b = (int)((unsigned)dstA[base + i] / NPB);  // magic-mul div
        atomicAdd(&h[b], 1);
    }
    __syncthreads();
    if (t < KB) cur[t] = atomicAdd(&gcur[t], h[t]);     // reserve fat run
    __syncthreads();
    for (int i = t; i < CHUNK_EDGES; i += 512) {
        int e = base + i;
        int d = dstA[e];                                // L2-hot re-read
        int b = (int)((unsigned)d / NPB);
        int dl = d - b * NPB;
        int p = atomicAdd(&cur[b], 1);
        if (p < ECAP)
            coarse[b * ECAP + p] = make_int2(src[e] | (dl << 18),
                                             __float_as_int(vals[e]));
    }
}

// P4F: per-super-bucket fine sort IN PLACE. Edges -> LDS (one read),
// histogram over 586 node counters, wave-shuffle scan, rowinfo emit,
// sorted scatter back into the same region.
__global__ __launch_bounds__(1024) void p4f_fine(int2* __restrict__ coarse,
                                                 const int* __restrict__ gcur,
                                                 uint* __restrict__ rowinfo) {
    __shared__ int2 eds[ECAP];        // 81920 B
    __shared__ int cnt[640];
    __shared__ int rs_[640];
    __shared__ int cur_[640];
    __shared__ int wsum[16];
    int k = blockIdx.x, t = threadIdx.x;
    int rbase = k * ECAP;
    int ne = min(gcur[k], ECAP);
    for (int i = t; i < ne; i += 1024) eds[i] = coarse[rbase + i];
    if (t < 640) cnt[t] = 0;
    __syncthreads();
    for (int i = t; i < ne; i += 1024)
        atomicAdd(&cnt[eds[i].x >> 18], 1);
    __syncthreads();
    int wid = t >> 6, lane = t & 63;
    if (t < 640) {                    // waves 0..9 (640 = 10*64)
        int v = cnt[t];
        int incl = v;
#pragma unroll
        for (int o = 1; o < 64; o <<= 1) {
            int add = __shfl_up(incl, o, 64);
            if (lane >= o) incl += add;
        }
        rs_[t] = incl - v;
        if (lane == 63) wsum[wid] = incl;
    }
    __syncthreads();
    if (t < 64) {
        int vv = (lane < 10) ? wsum[lane] : 0;
        int inc2 = vv;
#pragma unroll
        for (int o = 1; o < 16; o <<= 1) {
            int add = __shfl_up(inc2, o, 64);
            if (lane >= o) inc2 += add;
        }
        if (lane < 10) wsum[lane] = inc2 - vv;
    }
    __syncthreads();
    if (t < 640) rs_[t] += wsum[wid];
    __syncthreads();
    int nodes0 = k * NPB;
    int nb = min(NPB, N_NODES - nodes0);
    if (t < nb)
        rowinfo[nodes0 + t] = (uint)(rbase + rs_[t]) | ((uint)cnt[t] << 22);
    if (t < 640) cur_[t] = rs_[t];
    __syncthreads();
    for (int i = t; i < ne; i += 1024) {
        int2 ev = eds[i];
        int dl = ev.x >> 18;
        int p = atomicAdd(&cur_[dl], 1);
        coarse[rbase + p] = make_int2(ev.x & 0x3FFFF, ev.y);   // strip dl
    }
}

// SpMM over bf16 rows (128B/row). R6/R10 form: one wave per node; 8 groups
// x 8 lanes; 2x unrolled -> 16 edges in flight; shfl_xor reduce.
__global__ __launch_bounds__(256) void spmm_kernel(
        const uint* __restrict__ rowinfo, const int2* __restrict__ epair,
        const uint* __restrict__ xin, uint* __restrict__ xout) {
    int n = (blockIdx.x * 256 + threadIdx.x) >> 6;   // 150000 = 4*37500 exact
    int lane = threadIdx.x & 63;
    int g = lane >> 3;
    int l = lane & 7;
    uint ri = rowinfo[n];
    int s = (int)(ri & 0x3FFFFFu);
    int e = s + (int)(ri >> 22);
    v2f a0 = {0.f, 0.f}, a1 = {0.f, 0.f}, a2 = {0.f, 0.f}, a3 = {0.f, 0.f};
    for (int j0 = s + g; j0 < e; j0 += 16) {
        int j1 = j0 + 8;
        bool p1 = j1 < e;
        int2 ev0 = epair[j0];
        int2 ev1 = epair[p1 ? j1 : j0];
        float v0 = __int_as_float(ev0.y);
        float v1 = p1 ? __int_as_float(ev1.y) : 0.f;
        uint4 r0 = ((const uint4*)(xin + (size_t)ev0.x * 32))[l];
        uint4 r1 = ((const uint4*)(xin + (size_t)ev1.x * 32))[l];
        a0 += v0 * unpack_bf16x2(r0.x);
        a1 += v0 * unpack_bf16x2(r0.y);
        a2 += v0 * unpack_bf16x2(r0.z);
        a3 += v0 * unpack_bf16x2(r0.w);
        a0 += v1 * unpack_bf16x2(r1.x);
        a1 += v1 * unpack_bf16x2(r1.y);
        a2 += v1 * unpack_bf16x2(r1.z);
        a3 += v1 * unpack_bf16x2(r1.w);
    }
#pragma unroll
    for (int off = 8; off < 64; off <<= 1) {
        a0.x += __shfl_xor(a0.x, off, 64);
        a0.y += __shfl_xor(a0.y, off, 64);
        a1.x += __shfl_xor(a1.x, off, 64);
        a1.y += __shfl_xor(a1.y, off, 64);
        a2.x += __shfl_xor(a2.x, off, 64);
        a2.y += __shfl_xor(a2.y, off, 64);
        a3.x += __shfl_xor(a3.x, off, 64);
        a3.y += __shfl_xor(a3.y, off, 64);
    }
    if (g == 0) {
        uint4 o;
        o.x = pack_bf16(a0.x, a0.y);
        o.y = pack_bf16(a1.x, a1.y);
        o.z = pack_bf16(a2.x, a2.y);
        o.w = pack_bf16(a3.x, a3.y);
        ((uint4*)(xout + (size_t)n * 32))[l] = o;
    }
}

// Layer-3 restricted to batch rows: one wave per batch node (2*BATCH waves).
// x3[n] = sum val*x2[src]; add x0 (fp32) + x1 + x2 (bf16); store fp32 row.
__global__ __launch_bounds__(256) void batch_row_kernel(
        const int* __restrict__ users, const int* __restrict__ items,
        const float* __restrict__ emb_user, const float* __restrict__ emb_item,
        const uint* __restrict__ x1, const uint* __restrict__ x2,
        const uint* __restrict__ rowinfo, const int2* __restrict__ epair,
        float4* __restrict__ rows) {
    int w = (blockIdx.x * 256 + threadIdx.x) >> 6;   // 0..2*BATCH-1
    int lane = threadIdx.x & 63;
    int g = lane >> 4;
    int l = lane & 15;        // uint2 slot: dims 4l..4l+3
    bool isU = w < BATCH;
    int b = isU ? w : w - BATCH;
    int idx = isU ? users[b] : items[b];
    int n = isU ? idx : N_USERS + idx;
    uint ri = rowinfo[n];
    int s = (int)(ri & 0x3FFFFFu);
    int e = s + (int)(ri >> 22);
    v2f a0 = {0.f, 0.f}, a1 = {0.f, 0.f};
    for (int j0 = s + g; j0 < e; j0 += 16) {
        int2 ev[4];
        float vv[4];
        uint2 rr[4];
#pragma unroll
        for (int u = 0; u < 4; ++u) {
            int j = j0 + 4 * u;
            bool p = (u == 0) || (j < e);
            ev[u] = epair[p ? j : j0];
            vv[u] = p ? __int_as_float(ev[u].y) : 0.f;
        }
#pragma unroll
        for (int u = 0; u < 4; ++u)
            rr[u] = ((const uint2*)(x2 + (size_t)ev[u].x * 32))[l];
#pragma unroll
        for (int u = 0; u < 4; ++u) {
            a0 += vv[u] * unpack_bf16x2(rr[u].x);
            a1 += vv[u] * unpack_bf16x2(rr[u].y);
        }
    }
#pragma unroll
    for (int off = 16; off < 64; off <<= 1) {
        a0.x += __shfl_xor(a0.x, off, 64);
        a0.y += __shfl_xor(a0.y, off, 64);
        a1.x += __shfl_xor(a1.x, off, 64);
        a1.y += __shfl_xor(a1.y, off, 64);
    }
    if (g == 0) {
        const float* t0row = isU ? (emb_user + (size_t)idx * DIM)
                                 : (emb_item + (size_t)idx * DIM);
        float4 x0 = ((const float4*)t0row)[l];
        uint2 w1 = ((const uint2*)(x1 + (size_t)n * 32))[l];
        uint2 w2 = ((const uint2*)(x2 + (size_t)n * 32))[l];
        v2f b10 = unpack_bf16x2(w1.x), b11 = unpack_bf16x2(w1.y);
        v2f b20 = unpack_bf16x2(w2.x), b21 = unpack_bf16x2(w2.y);
        float4 r;
        r.x = x0.x + b10.x + b20.x + a0.x;
        r.y = x0.y + b10.y + b20.y + a0.y;
        r.z = x0.z + b11.x + b21.x + a1.x;
        r.w = x0.w + b11.y + b21.y + a1.y;
        rows[(size_t)w * 16 + l] = r;
    }
}

// gamma[b] = dot(rows[b], rows[BATCH+b]) / 16
__global__ __launch_bounds__(256) void dot_kernel(const float* __restrict__ rows,
                                                  float* __restrict__ out) {
    int t = blockIdx.x * 256 + threadIdx.x;
    int b = t >> 6;
    int lane = t & 63;
    float p = rows[(size_t)b * DIM + lane] * rows[(size_t)(BATCH + b) * DIM + lane];
#pragma unroll
    for (int o = 32; o > 0; o >>= 1) p += __shfl_down(p, o, 64);
    if (lane == 0) out[b] = p * (1.0f / 16.0f);
}

extern "C" void kernel_launch(void* const* d_in, const int* in_sizes, int n_in,
                              void* d_out, int out_size, void* d_ws, size_t ws_size,
                              hipStream_t stream) {
    const float* emb_user = (const float*)d_in[0];
    const float* emb_item = (const float*)d_in[1];
    const float* vals     = (const float*)d_in[2];
    const int*   src      = (const int*)d_in[3];
    const int*   dst      = (const int*)d_in[4];
    const int*   users    = (const int*)d_in[5];
    const int*   items    = (const int*)d_in[6];
    float* out = (float*)d_out;

    char* ws = (char*)d_ws;
    size_t off = 0;
    auto walloc = [&](size_t bytes) -> void* {
        void* p = ws + off;
        off += (bytes + 255) & ~(size_t)255;
        return p;
    };
    const size_t ROWB = (size_t)N_NODES * DIM * 2;                  // 19.2 MB
    uint* t0          = (uint*)walloc(ROWB);                        // bf16 x0
    uint* x1          = (uint*)walloc(ROWB);
    uint* x2          = (uint*)walloc(ROWB);
    int2* coarse      = (int2*)walloc((size_t)KB * ECAP * 8);       // 21.0 MB
    int*  gcur        = (int*) walloc((size_t)KB * 4);
    uint* rowinfo     = (uint*)walloc((size_t)N_NODES * 4);
    float4* rows      = (float4*)walloc((size_t)2 * BATCH * DIM * 4); // 2 MB

    hipMemsetAsync(gcur, 0, (size_t)KB * 4, stream);

    // Build: single-pass partition (+ fused conv), then in-place fine sort
    part_kernel<<<CHUNKS + CONVB, 512, 0, stream>>>(
        src, dst, vals, gcur, coarse, emb_user, emb_item, (uint2*)t0);
    p4f_fine<<<KB, 1024, 0, stream>>>(coarse, gcur, rowinfo);

    // Layers 1,2 full; layer 3 batch-only + dot
    spmm_kernel<<<N_NODES / 4, 256, 0, stream>>>(rowinfo, coarse, t0, x1);
    spmm_kernel<<<N_NODES / 4, 256, 0, stream>>>(rowinfo, coarse, x1, x2);
    batch_row_kernel<<<(2 * BATCH) / 4, 256, 0, stream>>>(
        users, items, emb_user, emb_item, x1, x2, rowinfo, coarse, rows);
    dot_kernel<<<(BATCH * 64) / 256, 256, 0, stream>>>((const float*)rows, out);
}